// Round 1
// baseline (1301.552 us; speedup 1.0000x reference)
//
#include <hip/hip_runtime.h>
#include <hip/hip_bf16.h>
#include <math.h>

// Problem constants (from reference)
constexpr int N_USERS = 100000;
constexpr int N_ENT   = 100000;
constexpr int DIM     = 64;
constexpr int HID     = 128;
constexpr int NEDGE   = 1600000;
constexpr int BATCH   = 8192;

// ---------------------------------------------------------------------------
// K1: degree histogram (int counts into degi, pre-zeroed by memset)
__global__ __launch_bounds__(256) void deg_count(const int* __restrict__ edges,
                                                 int* __restrict__ degi) {
    int e = blockIdx.x * 256 + threadIdx.x;
    if (e < NEDGE) {
        int dst = edges[NEDGE + e];
        atomicAdd(&degi[dst], 1);
    }
}

// K2: dinv[n] = 1/sqrt(deg+1), in place over the int counts
__global__ __launch_bounds__(256) void finalize_dinv(float* __restrict__ dinv) {
    int n = blockIdx.x * 256 + threadIdx.x;
    if (n < N_ENT) {
        int cnt = ((const int*)dinv)[n];
        dinv[n] = 1.0f / sqrtf((float)(cnt + 1));
    }
}

// ---------------------------------------------------------------------------
// K3: h1 = renorm(entity_emb) @ W1   [N,64]@[64,128] -> [N,128]
// W1 (32KB) lives in LDS; renorm scale applied to output rows.
__global__ __launch_bounds__(256) void gemm1_renorm(const float* __restrict__ emb,
                                                    const float* __restrict__ W1g,
                                                    float* __restrict__ h1) {
    __shared__ float W[64 * 128];
    __shared__ float A[16 * 65];     // +1 pad
    __shared__ float scales[16];
    int tid = threadIdx.x;
    for (int idx = tid; idx < 64 * 128; idx += 256) W[idx] = W1g[idx];
    int row0 = blockIdx.x * 16;
    for (int idx = tid; idx < 16 * 64; idx += 256) {
        int r = idx >> 6, c = idx & 63;
        A[r * 65 + c] = emb[(row0 + r) * 64 + c];
    }
    __syncthreads();
    if (tid < 16) {
        float s = 0.f;
#pragma unroll
        for (int k = 0; k < 64; ++k) { float a = A[tid * 65 + k]; s += a * a; }
        float nrm = sqrtf(s);
        scales[tid] = nrm > 1.0f ? 1.0f / nrm : 1.0f;   // min(1, 1/max(nrm,1e-12))
    }
    __syncthreads();
    int c    = tid & 127;
    int half = tid >> 7;          // 0/1 -> rows half*8 .. +7
    float acc[8];
#pragma unroll
    for (int r = 0; r < 8; ++r) acc[r] = 0.f;
    for (int k = 0; k < 64; ++k) {
        float w = W[k * 128 + c];
#pragma unroll
        for (int r = 0; r < 8; ++r) acc[r] += A[(half * 8 + r) * 65 + k] * w;
    }
#pragma unroll
    for (int r = 0; r < 8; ++r) {
        int rr = half * 8 + r;
        h1[(size_t)(row0 + rr) * 128 + c] = acc[r] * scales[rr];
    }
}

// K4: y1 = h1 * (1/deg) + b1   (self-loop + bias init before scatter)
__global__ __launch_bounds__(256) void init1(const float* __restrict__ h1,
                                             const float* __restrict__ dinv,
                                             const float* __restrict__ b1,
                                             float* __restrict__ y1) {
    int idx  = blockIdx.x * 256 + threadIdx.x;  // one float4 each; N*128/4 total
    int base = idx * 4;
    int row  = base >> 7;
    int col  = base & 127;
    float id = dinv[row]; id = id * id;         // 1/deg
    float4 h = *(const float4*)(h1 + base);
    float4 b = *(const float4*)(b1 + col);
    float4 o;
    o.x = h.x * id + b.x; o.y = h.y * id + b.y;
    o.z = h.z * id + b.z; o.w = h.w * id + b.w;
    *(float4*)(y1 + base) = o;
}

// K5: scatter layer 1 — one wave per edge, 128 dims (2 per lane)
__global__ __launch_bounds__(256) void scatter1(const int* __restrict__ edges,
                                                const float* __restrict__ dinv,
                                                const float* __restrict__ h1,
                                                float* __restrict__ y1) {
    int gt   = blockIdx.x * 256 + threadIdx.x;
    int w    = gt >> 6;                // edge index
    int lane = threadIdx.x & 63;
    int src = edges[w];
    int dst = edges[NEDGE + w];
    float nrm = dinv[src] * dinv[dst];
    const float* hp = h1 + (size_t)src * 128;
    float*       yp = y1 + (size_t)dst * 128;
    atomicAdd(yp + lane,      hp[lane]      * nrm);
    atomicAdd(yp + lane + 64, hp[lane + 64] * nrm);
}

// K6: h2 = relu(y1) @ W2   [N,128]@[128,64] -> [N,64], relu fused on load
__global__ __launch_bounds__(256) void gemm2_relu(const float* __restrict__ y1,
                                                  const float* __restrict__ W2g,
                                                  float* __restrict__ h2) {
    __shared__ float W[128 * 64];
    __shared__ float A[16 * 129];    // +1 pad
    int tid = threadIdx.x;
    for (int idx = tid; idx < 128 * 64; idx += 256) W[idx] = W2g[idx];
    int row0 = blockIdx.x * 16;
    for (int idx = tid; idx < 16 * 128; idx += 256) {
        int r = idx >> 7, c = idx & 127;
        float v = y1[(size_t)(row0 + r) * 128 + c];
        A[r * 129 + c] = v > 0.f ? v : 0.f;
    }
    __syncthreads();
    int c   = tid & 63;
    int grp = tid >> 6;              // 0..3 -> rows grp*4 .. +3
    float acc[4];
#pragma unroll
    for (int r = 0; r < 4; ++r) acc[r] = 0.f;
    for (int k = 0; k < 128; ++k) {
        float w = W[k * 64 + c];
#pragma unroll
        for (int r = 0; r < 4; ++r) acc[r] += A[(grp * 4 + r) * 129 + k] * w;
    }
#pragma unroll
    for (int r = 0; r < 4; ++r)
        h2[(size_t)(row0 + grp * 4 + r) * 64 + c] = acc[r];
}

// K7: y2 = h2 * (1/deg) + b2
__global__ __launch_bounds__(256) void init2(const float* __restrict__ h2,
                                             const float* __restrict__ dinv,
                                             const float* __restrict__ b2,
                                             float* __restrict__ y2) {
    int idx  = blockIdx.x * 256 + threadIdx.x;  // one float4 each; N*64/4 total
    int base = idx * 4;
    int row  = base >> 6;
    int col  = base & 63;
    float id = dinv[row]; id = id * id;
    float4 h = *(const float4*)(h2 + base);
    float4 b = *(const float4*)(b2 + col);
    float4 o;
    o.x = h.x * id + b.x; o.y = h.y * id + b.y;
    o.z = h.z * id + b.z; o.w = h.w * id + b.w;
    *(float4*)(y2 + base) = o;
}

// K8: scatter layer 2 — one wave per edge, 64 dims (1 per lane)
__global__ __launch_bounds__(256) void scatter2(const int* __restrict__ edges,
                                                const float* __restrict__ dinv,
                                                const float* __restrict__ h2,
                                                float* __restrict__ y2) {
    int gt   = blockIdx.x * 256 + threadIdx.x;
    int w    = gt >> 6;
    int lane = threadIdx.x & 63;
    int src = edges[w];
    int dst = edges[NEDGE + w];
    float nrm = dinv[src] * dinv[dst];
    atomicAdd(y2 + (size_t)dst * 64 + lane, h2[(size_t)src * 64 + lane] * nrm);
}

// K9: final — one wave per batch element: renorm(user)·item, sigmoid
__global__ __launch_bounds__(256) void final_dot(const int* __restrict__ u,
                                                 const int* __restrict__ iidx,
                                                 const float* __restrict__ uemb,
                                                 const float* __restrict__ y2,
                                                 float* __restrict__ out) {
    int gt   = blockIdx.x * 256 + threadIdx.x;
    int b    = gt >> 6;
    int lane = threadIdx.x & 63;
    int ui = u[b];
    int it = iidx[b];
    float ue = uemb[(size_t)ui * 64 + lane];
    float iv = y2[(size_t)it * 64 + lane];
    float s1 = ue * ue;
    float s2 = ue * iv;
#pragma unroll
    for (int o = 32; o > 0; o >>= 1) {
        s1 += __shfl_xor(s1, o, 64);
        s2 += __shfl_xor(s2, o, 64);
    }
    if (lane == 0) {
        float nrm = sqrtf(s1);
        float sc  = nrm > 1.0f ? 1.0f / nrm : 1.0f;
        float uv  = s2 * sc;
        out[b] = 1.0f / (1.0f + expf(-uv));
    }
}

// ---------------------------------------------------------------------------
extern "C" void kernel_launch(void* const* d_in, const int* in_sizes, int n_in,
                              void* d_out, int out_size, void* d_ws, size_t ws_size,
                              hipStream_t stream) {
    const int*   u          = (const int*)d_in[0];
    const int*   iidx       = (const int*)d_in[1];
    const int*   edges      = (const int*)d_in[2];
    const float* user_emb   = (const float*)d_in[3];
    const float* entity_emb = (const float*)d_in[4];
    const float* W1         = (const float*)d_in[5];
    const float* b1         = (const float*)d_in[6];
    const float* W2         = (const float*)d_in[7];
    const float* b2         = (const float*)d_in[8];
    float*       out        = (float*)d_out;

    // Workspace layout (floats):
    //  dinv : [0, N)                      (int counts, then float dinv)
    //  h    : [N, N + N*128)              h1; later h2 = first N*64, y2 = second N*64
    //  y1   : [N + N*128, N + N*256)
    float* ws   = (float*)d_ws;
    float* dinv = ws;
    float* h    = ws + N_ENT;
    float* y1   = ws + N_ENT + (size_t)N_ENT * 128;
    float* h2   = h;
    float* y2   = h + (size_t)N_ENT * 64;

    hipMemsetAsync(dinv, 0, N_ENT * sizeof(int), stream);
    deg_count<<<(NEDGE + 255) / 256, 256, 0, stream>>>(edges, (int*)dinv);
    finalize_dinv<<<(N_ENT + 255) / 256, 256, 0, stream>>>(dinv);

    gemm1_renorm<<<N_ENT / 16, 256, 0, stream>>>(entity_emb, W1, h);
    init1<<<(N_ENT * 128 / 4) / 256, 256, 0, stream>>>(h, dinv, b1, y1);
    scatter1<<<(NEDGE * 64) / 256, 256, 0, stream>>>(edges, dinv, h, y1);

    gemm2_relu<<<N_ENT / 16, 256, 0, stream>>>(y1, W2, h2);
    init2<<<(N_ENT * 64 / 4) / 256, 256, 0, stream>>>(h2, dinv, b2, y2);
    scatter2<<<(NEDGE * 64) / 256, 256, 0, stream>>>(edges, dinv, h2, y2);

    final_dot<<<(BATCH * 64) / 256, 256, 0, stream>>>(u, iidx, user_emb, y2, out);
}

// Round 2
// 840.819 us; speedup vs baseline: 1.5480x; 1.5480x over previous
//
#include <hip/hip_runtime.h>
#include <hip/hip_bf16.h>
#include <math.h>

// Problem constants (from reference)
constexpr int N_ENT = 100000;
constexpr int NEDGE = 1600000;
constexpr int BATCH = 8192;

// ---------------------------------------------------------------------------
// Workspace layout (4-byte units):
//  degi      : [0, 100000)            int   degree counts
//  dinv      : [100000, 200000)       float 1/sqrt(deg+1)
//  scale     : [200000, 300000)       float renorm scale per entity
//  row_start : [300000, 400001)       int   CSR offsets (100001)
//  cursor    : [400004, 500004)       int   placement cursors
//  src_sorted: [500004, 2100004)      int   CSR src ids
//  fs1       : [2100004, 3700004)     float scale[s]*dinv[s] per CSR slot
//  dvs       : [3700004, 5300004)     float dinv[s] per CSR slot
//  z / h2    : [5300008, 11700008)    float [N,64] (z, then reused as h2)
//  y1r / z2  : [11700008, 24500008)   float [N,128] y1r, then z2 in first half
// Total ~98 MB (round-1 layout used 102.8 MB successfully).

// K1: degree histogram
__global__ __launch_bounds__(256) void deg_count(const int* __restrict__ edges,
                                                 int* __restrict__ degi) {
    int e = blockIdx.x * 256 + threadIdx.x;
    if (e < NEDGE) atomicAdd(&degi[edges[NEDGE + e]], 1);
}

// K2: dinv = 1/sqrt(deg+1)
__global__ __launch_bounds__(256) void dinv_k(const int* __restrict__ degi,
                                              float* __restrict__ dinv) {
    int n = blockIdx.x * 256 + threadIdx.x;
    if (n < N_ENT) dinv[n] = 1.0f / sqrtf((float)(degi[n] + 1));
}

// K3: per-entity renorm scale = min(1, 1/max(norm,1e-12)) — one wave per row
__global__ __launch_bounds__(256) void scale_k(const float* __restrict__ emb,
                                               float* __restrict__ scale) {
    int gt   = blockIdx.x * 256 + threadIdx.x;
    int n    = gt >> 6;
    int lane = threadIdx.x & 63;
    float v = emb[(size_t)n * 64 + lane];
    float s = v * v;
#pragma unroll
    for (int o = 32; o > 0; o >>= 1) s += __shfl_xor(s, o, 64);
    if (lane == 0) {
        float nrm = sqrtf(s);
        scale[n] = nrm > 1.0f ? 1.0f / nrm : 1.0f;
    }
}

// K4: single-block exclusive scan of degi -> row_start (+ cursor copy)
__global__ __launch_bounds__(1024) void scan_k(const int* __restrict__ degi,
                                               int* __restrict__ row_start,
                                               int* __restrict__ cursor) {
    constexpr int T = 1024;
    constexpr int PER = (N_ENT + T - 1) / T;   // 98
    __shared__ int ts[T];
    int t  = threadIdx.x;
    int lo = t * PER;
    int hi = lo + PER; if (hi > N_ENT) hi = N_ENT; if (lo > N_ENT) lo = N_ENT;
    int s = 0;
    for (int i = lo; i < hi; ++i) s += degi[i];
    ts[t] = s;
    __syncthreads();
    // Hillis-Steele inclusive scan
    for (int off = 1; off < T; off <<= 1) {
        int v = (t >= off) ? ts[t - off] : 0;
        __syncthreads();
        ts[t] += v;
        __syncthreads();
    }
    int run = ts[t] - s;   // exclusive prefix for this chunk
    for (int i = lo; i < hi; ++i) {
        row_start[i] = run;
        cursor[i]    = run;
        run += degi[i];
    }
    if (t == T - 1) row_start[N_ENT] = run;   // == NEDGE
}

// K5: CSR placement — also precompute per-edge factors
__global__ __launch_bounds__(256) void place_k(const int* __restrict__ edges,
                                               const float* __restrict__ dinv,
                                               const float* __restrict__ scale,
                                               int* __restrict__ cursor,
                                               int* __restrict__ srcs,
                                               float* __restrict__ fs1,
                                               float* __restrict__ dvs) {
    int e = blockIdx.x * 256 + threadIdx.x;
    if (e >= NEDGE) return;
    int s = edges[e];
    int d = edges[NEDGE + e];
    int pos = atomicAdd(&cursor[d], 1);
    srcs[pos] = s;
    float ds = dinv[s];
    fs1[pos] = scale[s] * ds;
    dvs[pos] = ds;
}

// K6: layer-1 aggregate on RAW 64-dim input (scatter commuted before GEMM):
// z[d] = dinv[d] * sum_j fs1[j]*emb[src_j] + scale[d]*dinv[d]^2 * emb[d]
__global__ __launch_bounds__(256) void reduce1_k(const int* __restrict__ row_start,
                                                 const int* __restrict__ srcs,
                                                 const float* __restrict__ fs1,
                                                 const float* __restrict__ emb,
                                                 const float* __restrict__ dinv,
                                                 const float* __restrict__ scale,
                                                 float* __restrict__ z) {
    int gt   = blockIdx.x * 256 + threadIdx.x;
    int dst  = gt >> 6;
    int lane = threadIdx.x & 63;
    int beg = row_start[dst];
    int end = row_start[dst + 1];
    float acc0 = 0.f, acc1 = 0.f;
    int j = beg;
    for (; j + 1 < end; j += 2) {
        int   s0 = srcs[j],  s1 = srcs[j + 1];
        float f0 = fs1[j],   f1 = fs1[j + 1];
        acc0 += f0 * emb[(size_t)s0 * 64 + lane];
        acc1 += f1 * emb[(size_t)s1 * 64 + lane];
    }
    if (j < end) acc0 += fs1[j] * emb[(size_t)srcs[j] * 64 + lane];
    float dv   = dinv[dst];
    float self = scale[dst] * dv * dv;
    z[(size_t)dst * 64 + lane] = dv * (acc0 + acc1) + self * emb[(size_t)dst * 64 + lane];
}

// K7: y1r = relu(z @ W1 + b1)   [N,64]@[64,128]
__global__ __launch_bounds__(256) void gemm1_relu(const float* __restrict__ z,
                                                  const float* __restrict__ W1g,
                                                  const float* __restrict__ b1,
                                                  float* __restrict__ y1r) {
    __shared__ float W[64 * 128];
    __shared__ float A[16 * 65];     // +1 pad
    int tid = threadIdx.x;
    for (int idx = tid; idx < 64 * 128; idx += 256) W[idx] = W1g[idx];
    int row0 = blockIdx.x * 16;
    for (int idx = tid; idx < 16 * 64; idx += 256) {
        int r = idx >> 6, c = idx & 63;
        A[r * 65 + c] = z[(size_t)(row0 + r) * 64 + c];
    }
    __syncthreads();
    int c    = tid & 127;
    int half = tid >> 7;
    float acc[8];
#pragma unroll
    for (int r = 0; r < 8; ++r) acc[r] = 0.f;
    for (int k = 0; k < 64; ++k) {
        float w = W[k * 128 + c];
#pragma unroll
        for (int r = 0; r < 8; ++r) acc[r] += A[(half * 8 + r) * 65 + k] * w;
    }
    float bb = b1[c];
#pragma unroll
    for (int r = 0; r < 8; ++r) {
        float v = acc[r] + bb;
        y1r[(size_t)(row0 + half * 8 + r) * 128 + c] = v > 0.f ? v : 0.f;
    }
}

// K8: h2 = y1r @ W2   [N,128]@[128,64] (input already relu'd; no bias here)
__global__ __launch_bounds__(256) void gemm2_k(const float* __restrict__ y1r,
                                               const float* __restrict__ W2g,
                                               float* __restrict__ h2) {
    __shared__ float W[128 * 64];
    __shared__ float A[16 * 129];    // +1 pad
    int tid = threadIdx.x;
    for (int idx = tid; idx < 128 * 64; idx += 256) W[idx] = W2g[idx];
    int row0 = blockIdx.x * 16;
    for (int idx = tid; idx < 16 * 128; idx += 256) {
        int r = idx >> 7, c = idx & 127;
        A[r * 129 + c] = y1r[(size_t)(row0 + r) * 128 + c];
    }
    __syncthreads();
    int c   = tid & 63;
    int grp = tid >> 6;
    float acc[4];
#pragma unroll
    for (int r = 0; r < 4; ++r) acc[r] = 0.f;
    for (int k = 0; k < 128; ++k) {
        float w = W[k * 64 + c];
#pragma unroll
        for (int r = 0; r < 4; ++r) acc[r] += A[(grp * 4 + r) * 129 + k] * w;
    }
#pragma unroll
    for (int r = 0; r < 4; ++r)
        h2[(size_t)(row0 + grp * 4 + r) * 64 + c] = acc[r];
}

// K9: layer-2 aggregate:
// z2[d] = dinv[d]*sum_j dvs[j]*h2[src_j] + dinv[d]^2*h2[d] + b2
__global__ __launch_bounds__(256) void reduce2_k(const int* __restrict__ row_start,
                                                 const int* __restrict__ srcs,
                                                 const float* __restrict__ dvs,
                                                 const float* __restrict__ h2,
                                                 const float* __restrict__ dinv,
                                                 const float* __restrict__ b2,
                                                 float* __restrict__ z2) {
    int gt   = blockIdx.x * 256 + threadIdx.x;
    int dst  = gt >> 6;
    int lane = threadIdx.x & 63;
    int beg = row_start[dst];
    int end = row_start[dst + 1];
    float acc0 = 0.f, acc1 = 0.f;
    int j = beg;
    for (; j + 1 < end; j += 2) {
        int   s0 = srcs[j],  s1 = srcs[j + 1];
        float f0 = dvs[j],   f1 = dvs[j + 1];
        acc0 += f0 * h2[(size_t)s0 * 64 + lane];
        acc1 += f1 * h2[(size_t)s1 * 64 + lane];
    }
    if (j < end) acc0 += dvs[j] * h2[(size_t)srcs[j] * 64 + lane];
    float dv = dinv[dst];
    z2[(size_t)dst * 64 + lane] =
        dv * (acc0 + acc1) + dv * dv * h2[(size_t)dst * 64 + lane] + b2[lane];
}

// K10: final — renorm(user)·item, sigmoid; one wave per batch element
__global__ __launch_bounds__(256) void final_dot(const int* __restrict__ u,
                                                 const int* __restrict__ iidx,
                                                 const float* __restrict__ uemb,
                                                 const float* __restrict__ z2,
                                                 float* __restrict__ out) {
    int gt   = blockIdx.x * 256 + threadIdx.x;
    int b    = gt >> 6;
    int lane = threadIdx.x & 63;
    int ui = u[b];
    int it = iidx[b];
    float ue = uemb[(size_t)ui * 64 + lane];
    float iv = z2[(size_t)it * 64 + lane];
    float s1 = ue * ue;
    float s2 = ue * iv;
#pragma unroll
    for (int o = 32; o > 0; o >>= 1) {
        s1 += __shfl_xor(s1, o, 64);
        s2 += __shfl_xor(s2, o, 64);
    }
    if (lane == 0) {
        float nrm = sqrtf(s1);
        float sc  = nrm > 1.0f ? 1.0f / nrm : 1.0f;
        float uv  = s2 * sc;
        out[b] = 1.0f / (1.0f + expf(-uv));
    }
}

// ---------------------------------------------------------------------------
extern "C" void kernel_launch(void* const* d_in, const int* in_sizes, int n_in,
                              void* d_out, int out_size, void* d_ws, size_t ws_size,
                              hipStream_t stream) {
    const int*   u          = (const int*)d_in[0];
    const int*   iidx       = (const int*)d_in[1];
    const int*   edges      = (const int*)d_in[2];
    const float* user_emb   = (const float*)d_in[3];
    const float* entity_emb = (const float*)d_in[4];
    const float* W1         = (const float*)d_in[5];
    const float* b1         = (const float*)d_in[6];
    const float* W2         = (const float*)d_in[7];
    const float* b2         = (const float*)d_in[8];
    float*       out        = (float*)d_out;

    char* ws = (char*)d_ws;
    int*   degi      = (int*)  (ws);
    float* dinv      = (float*)(ws + 100000u * 4);
    float* scale     = (float*)(ws + 200000u * 4);
    int*   row_start = (int*)  (ws + 300000u * 4);
    int*   cursor    = (int*)  (ws + 400004u * 4);
    int*   srcs      = (int*)  (ws + 500004u * 4);
    float* fs1       = (float*)(ws + 2100004u * 4);
    float* dvs       = (float*)(ws + 3700004u * 4);
    float* z         = (float*)(ws + 5300008u * 4);   // reused as h2
    float* y1r       = (float*)(ws + 11700008u * 4);  // reused as z2
    float* h2 = z;
    float* z2 = y1r;

    hipMemsetAsync(degi, 0, N_ENT * sizeof(int), stream);
    deg_count<<<NEDGE / 256, 256, 0, stream>>>(edges, degi);
    dinv_k<<<(N_ENT + 255) / 256, 256, 0, stream>>>(degi, dinv);
    scale_k<<<N_ENT * 64 / 256, 256, 0, stream>>>(entity_emb, scale);
    scan_k<<<1, 1024, 0, stream>>>(degi, row_start, cursor);
    place_k<<<NEDGE / 256, 256, 0, stream>>>(edges, dinv, scale, cursor, srcs, fs1, dvs);

    reduce1_k<<<N_ENT * 64 / 256, 256, 0, stream>>>(row_start, srcs, fs1, entity_emb,
                                                    dinv, scale, z);
    gemm1_relu<<<N_ENT / 16, 256, 0, stream>>>(z, W1, b1, y1r);
    gemm2_k<<<N_ENT / 16, 256, 0, stream>>>(y1r, W2, h2);
    reduce2_k<<<N_ENT * 64 / 256, 256, 0, stream>>>(row_start, srcs, dvs, h2,
                                                    dinv, b2, z2);

    final_dot<<<BATCH * 64 / 256, 256, 0, stream>>>(u, iidx, user_emb, z2, out);
}

// Round 3
// 614.566 us; speedup vs baseline: 2.1178x; 1.3682x over previous
//
#include <hip/hip_runtime.h>
#include <hip/hip_bf16.h>
#include <math.h>

// Problem constants (from reference)
constexpr int N_ENT = 100000;
constexpr int NEDGE = 1600000;
constexpr int BATCH = 8192;
constexpr int NBLK_SCAN = (N_ENT + 255) / 256;   // 391

// ---------------------------------------------------------------------------
// Workspace layout (4-byte units):
//  degi      : [0, 100000)            int   degree counts
//  dinv      : [100000, 200000)       float 1/sqrt(deg+1)
//  scale     : [200000, 300000)       float renorm scale per entity
//  row_start : [300000, 400001)       int   CSR offsets (100001)
//  cursor    : [400004, 500004)       int   placement cursors
//  partials  : [500004, 500404)       int   per-block degree sums (391)
//  src_sorted: [500404, 2100404)      int   CSR src ids
//  fs1       : [2100404, 3700404)     float scale[s]*dinv[s] per CSR slot
//  dvs       : [3700404, 5300404)     float dinv[s] per CSR slot
//  z / h2    : [5300408, 11700408)    float [N,64] (z, then reused as h2)
//  y1r / z2  : [11700408, 24500408)   float [N,128] y1r, then z2 in first half

// K1: degree histogram
__global__ __launch_bounds__(256) void deg_count(const int* __restrict__ edges,
                                                 int* __restrict__ degi) {
    int e = blockIdx.x * 256 + threadIdx.x;
    if (e < NEDGE) atomicAdd(&degi[edges[NEDGE + e]], 1);
}

// K2: dinv = 1/sqrt(deg+1)
__global__ __launch_bounds__(256) void dinv_k(const int* __restrict__ degi,
                                              float* __restrict__ dinv) {
    int n = blockIdx.x * 256 + threadIdx.x;
    if (n < N_ENT) dinv[n] = 1.0f / sqrtf((float)(degi[n] + 1));
}

// K3: per-entity renorm scale — one wave per row
__global__ __launch_bounds__(256) void scale_k(const float* __restrict__ emb,
                                               float* __restrict__ scale) {
    int gt   = blockIdx.x * 256 + threadIdx.x;
    int n    = gt >> 6;
    int lane = threadIdx.x & 63;
    float v = emb[(size_t)n * 64 + lane];
    float s = v * v;
#pragma unroll
    for (int o = 32; o > 0; o >>= 1) s += __shfl_xor(s, o, 64);
    if (lane == 0) {
        float nrm = sqrtf(s);
        scale[n] = nrm > 1.0f ? 1.0f / nrm : 1.0f;
    }
}

// K4a: per-block degree sums
__global__ __launch_bounds__(256) void scan_partials(const int* __restrict__ degi,
                                                     int* __restrict__ partials) {
    __shared__ int ws[4];
    int i = blockIdx.x * 256 + threadIdx.x;
    int v = (i < N_ENT) ? degi[i] : 0;
#pragma unroll
    for (int o = 32; o > 0; o >>= 1) v += __shfl_xor(v, o, 64);
    if ((threadIdx.x & 63) == 0) ws[threadIdx.x >> 6] = v;
    __syncthreads();
    if (threadIdx.x == 0) partials[blockIdx.x] = ws[0] + ws[1] + ws[2] + ws[3];
}

// K4b: single small block — exclusive scan of 391 partials (in place)
__global__ __launch_bounds__(512) void scan_offsets(int* __restrict__ partials,
                                                    int* __restrict__ row_start) {
    __shared__ int ts[512];
    int t = threadIdx.x;
    int v = (t < NBLK_SCAN) ? partials[t] : 0;
    ts[t] = v;
    __syncthreads();
    for (int off = 1; off < 512; off <<= 1) {
        int x = (t >= off) ? ts[t - off] : 0;
        __syncthreads();
        ts[t] += x;
        __syncthreads();
    }
    if (t < NBLK_SCAN) partials[t] = ts[t] - v;   // exclusive block offset
    if (t == 0) row_start[N_ENT] = NEDGE;
}

// K4c: per-block exclusive scan + block offset -> row_start, cursor
__global__ __launch_bounds__(256) void scan_apply(const int* __restrict__ degi,
                                                  const int* __restrict__ partials,
                                                  int* __restrict__ row_start,
                                                  int* __restrict__ cursor) {
    __shared__ int ts[256];
    int t = threadIdx.x;
    int i = blockIdx.x * 256 + t;
    int v = (i < N_ENT) ? degi[i] : 0;
    ts[t] = v;
    __syncthreads();
    for (int off = 1; off < 256; off <<= 1) {
        int x = (t >= off) ? ts[t - off] : 0;
        __syncthreads();
        ts[t] += x;
        __syncthreads();
    }
    if (i < N_ENT) {
        int excl = ts[t] - v + partials[blockIdx.x];
        row_start[i] = excl;
        cursor[i]    = excl;
    }
}

// K5: CSR placement — also precompute per-edge factors
__global__ __launch_bounds__(256) void place_k(const int* __restrict__ edges,
                                               const float* __restrict__ dinv,
                                               const float* __restrict__ scale,
                                               int* __restrict__ cursor,
                                               int* __restrict__ srcs,
                                               float* __restrict__ fs1,
                                               float* __restrict__ dvs) {
    int e = blockIdx.x * 256 + threadIdx.x;
    if (e >= NEDGE) return;
    int s = edges[e];
    int d = edges[NEDGE + e];
    int pos = atomicAdd(&cursor[d], 1);
    srcs[pos] = s;
    float ds = dinv[s];
    fs1[pos] = scale[s] * ds;
    dvs[pos] = ds;
}

// K6: layer-1 aggregate on RAW 64-dim input (scatter commuted before GEMM):
// z[d] = dinv[d] * sum_j fs1[j]*emb[src_j] + scale[d]*dinv[d]^2 * emb[d]
__global__ __launch_bounds__(256) void reduce1_k(const int* __restrict__ row_start,
                                                 const int* __restrict__ srcs,
                                                 const float* __restrict__ fs1,
                                                 const float* __restrict__ emb,
                                                 const float* __restrict__ dinv,
                                                 const float* __restrict__ scale,
                                                 float* __restrict__ z) {
    int gt   = blockIdx.x * 256 + threadIdx.x;
    int dst  = gt >> 6;
    int lane = threadIdx.x & 63;
    int beg = row_start[dst];
    int end = row_start[dst + 1];
    float acc0 = 0.f, acc1 = 0.f;
    int j = beg;
    for (; j + 1 < end; j += 2) {
        int   s0 = srcs[j],  s1 = srcs[j + 1];
        float f0 = fs1[j],   f1 = fs1[j + 1];
        acc0 += f0 * emb[(size_t)s0 * 64 + lane];
        acc1 += f1 * emb[(size_t)s1 * 64 + lane];
    }
    if (j < end) acc0 += fs1[j] * emb[(size_t)srcs[j] * 64 + lane];
    float dv   = dinv[dst];
    float self = scale[dst] * dv * dv;
    z[(size_t)dst * 64 + lane] = dv * (acc0 + acc1) + self * emb[(size_t)dst * 64 + lane];
}

// K7: y1r = relu(z @ W1 + b1)   [N,64]@[64,128]
__global__ __launch_bounds__(256) void gemm1_relu(const float* __restrict__ z,
                                                  const float* __restrict__ W1g,
                                                  const float* __restrict__ b1,
                                                  float* __restrict__ y1r) {
    __shared__ float W[64 * 128];
    __shared__ float A[16 * 65];     // +1 pad
    int tid = threadIdx.x;
    for (int idx = tid; idx < 64 * 128; idx += 256) W[idx] = W1g[idx];
    int row0 = blockIdx.x * 16;
    for (int idx = tid; idx < 16 * 64; idx += 256) {
        int r = idx >> 6, c = idx & 63;
        A[r * 65 + c] = z[(size_t)(row0 + r) * 64 + c];
    }
    __syncthreads();
    int c    = tid & 127;
    int half = tid >> 7;
    float acc[8];
#pragma unroll
    for (int r = 0; r < 8; ++r) acc[r] = 0.f;
    for (int k = 0; k < 64; ++k) {
        float w = W[k * 128 + c];
#pragma unroll
        for (int r = 0; r < 8; ++r) acc[r] += A[(half * 8 + r) * 65 + k] * w;
    }
    float bb = b1[c];
#pragma unroll
    for (int r = 0; r < 8; ++r) {
        float v = acc[r] + bb;
        y1r[(size_t)(row0 + half * 8 + r) * 128 + c] = v > 0.f ? v : 0.f;
    }
}

// K8: h2 = y1r @ W2   [N,128]@[128,64]
__global__ __launch_bounds__(256) void gemm2_k(const float* __restrict__ y1r,
                                               const float* __restrict__ W2g,
                                               float* __restrict__ h2) {
    __shared__ float W[128 * 64];
    __shared__ float A[16 * 129];    // +1 pad
    int tid = threadIdx.x;
    for (int idx = tid; idx < 128 * 64; idx += 256) W[idx] = W2g[idx];
    int row0 = blockIdx.x * 16;
    for (int idx = tid; idx < 16 * 128; idx += 256) {
        int r = idx >> 7, c = idx & 127;
        A[r * 129 + c] = y1r[(size_t)(row0 + r) * 128 + c];
    }
    __syncthreads();
    int c   = tid & 63;
    int grp = tid >> 6;
    float acc[4];
#pragma unroll
    for (int r = 0; r < 4; ++r) acc[r] = 0.f;
    for (int k = 0; k < 128; ++k) {
        float w = W[k * 64 + c];
#pragma unroll
        for (int r = 0; r < 4; ++r) acc[r] += A[(grp * 4 + r) * 129 + k] * w;
    }
#pragma unroll
    for (int r = 0; r < 4; ++r)
        h2[(size_t)(row0 + grp * 4 + r) * 64 + c] = acc[r];
}

// K9: layer-2 aggregate:
// z2[d] = dinv[d]*sum_j dvs[j]*h2[src_j] + dinv[d]^2*h2[d] + b2
__global__ __launch_bounds__(256) void reduce2_k(const int* __restrict__ row_start,
                                                 const int* __restrict__ srcs,
                                                 const float* __restrict__ dvs,
                                                 const float* __restrict__ h2,
                                                 const float* __restrict__ dinv,
                                                 const float* __restrict__ b2,
                                                 float* __restrict__ z2) {
    int gt   = blockIdx.x * 256 + threadIdx.x;
    int dst  = gt >> 6;
    int lane = threadIdx.x & 63;
    int beg = row_start[dst];
    int end = row_start[dst + 1];
    float acc0 = 0.f, acc1 = 0.f;
    int j = beg;
    for (; j + 1 < end; j += 2) {
        int   s0 = srcs[j],  s1 = srcs[j + 1];
        float f0 = dvs[j],   f1 = dvs[j + 1];
        acc0 += f0 * h2[(size_t)s0 * 64 + lane];
        acc1 += f1 * h2[(size_t)s1 * 64 + lane];
    }
    if (j < end) acc0 += dvs[j] * h2[(size_t)srcs[j] * 64 + lane];
    float dv = dinv[dst];
    z2[(size_t)dst * 64 + lane] =
        dv * (acc0 + acc1) + dv * dv * h2[(size_t)dst * 64 + lane] + b2[lane];
}

// K10: final — renorm(user)·item, sigmoid; one wave per batch element
__global__ __launch_bounds__(256) void final_dot(const int* __restrict__ u,
                                                 const int* __restrict__ iidx,
                                                 const float* __restrict__ uemb,
                                                 const float* __restrict__ z2,
                                                 float* __restrict__ out) {
    int gt   = blockIdx.x * 256 + threadIdx.x;
    int b    = gt >> 6;
    int lane = threadIdx.x & 63;
    int ui = u[b];
    int it = iidx[b];
    float ue = uemb[(size_t)ui * 64 + lane];
    float iv = z2[(size_t)it * 64 + lane];
    float s1 = ue * ue;
    float s2 = ue * iv;
#pragma unroll
    for (int o = 32; o > 0; o >>= 1) {
        s1 += __shfl_xor(s1, o, 64);
        s2 += __shfl_xor(s2, o, 64);
    }
    if (lane == 0) {
        float nrm = sqrtf(s1);
        float sc  = nrm > 1.0f ? 1.0f / nrm : 1.0f;
        float uv  = s2 * sc;
        out[b] = 1.0f / (1.0f + expf(-uv));
    }
}

// ---------------------------------------------------------------------------
extern "C" void kernel_launch(void* const* d_in, const int* in_sizes, int n_in,
                              void* d_out, int out_size, void* d_ws, size_t ws_size,
                              hipStream_t stream) {
    const int*   u          = (const int*)d_in[0];
    const int*   iidx       = (const int*)d_in[1];
    const int*   edges      = (const int*)d_in[2];
    const float* user_emb   = (const float*)d_in[3];
    const float* entity_emb = (const float*)d_in[4];
    const float* W1         = (const float*)d_in[5];
    const float* b1         = (const float*)d_in[6];
    const float* W2         = (const float*)d_in[7];
    const float* b2         = (const float*)d_in[8];
    float*       out        = (float*)d_out;

    char* ws = (char*)d_ws;
    int*   degi      = (int*)  (ws);
    float* dinv      = (float*)(ws + 100000u * 4);
    float* scale     = (float*)(ws + 200000u * 4);
    int*   row_start = (int*)  (ws + 300000u * 4);
    int*   cursor    = (int*)  (ws + 400004u * 4);
    int*   partials  = (int*)  (ws + 500004u * 4);
    int*   srcs      = (int*)  (ws + 500404u * 4);
    float* fs1       = (float*)(ws + 2100404u * 4);
    float* dvs       = (float*)(ws + 3700404u * 4);
    float* z         = (float*)(ws + 5300408u * 4);   // reused as h2
    float* y1r       = (float*)(ws + 11700408u * 4);  // reused as z2
    float* h2 = z;
    float* z2 = y1r;

    hipMemsetAsync(degi, 0, N_ENT * sizeof(int), stream);
    deg_count<<<NEDGE / 256, 256, 0, stream>>>(edges, degi);
    dinv_k<<<(N_ENT + 255) / 256, 256, 0, stream>>>(degi, dinv);
    scale_k<<<N_ENT * 64 / 256, 256, 0, stream>>>(entity_emb, scale);

    scan_partials<<<NBLK_SCAN, 256, 0, stream>>>(degi, partials);
    scan_offsets<<<1, 512, 0, stream>>>(partials, row_start);
    scan_apply<<<NBLK_SCAN, 256, 0, stream>>>(degi, partials, row_start, cursor);

    place_k<<<NEDGE / 256, 256, 0, stream>>>(edges, dinv, scale, cursor, srcs, fs1, dvs);

    reduce1_k<<<N_ENT * 64 / 256, 256, 0, stream>>>(row_start, srcs, fs1, entity_emb,
                                                    dinv, scale, z);
    gemm1_relu<<<N_ENT / 16, 256, 0, stream>>>(z, W1, b1, y1r);
    gemm2_k<<<N_ENT / 16, 256, 0, stream>>>(y1r, W2, h2);
    reduce2_k<<<N_ENT * 64 / 256, 256, 0, stream>>>(row_start, srcs, dvs, h2,
                                                    dinv, b2, z2);

    final_dot<<<BATCH * 64 / 256, 256, 0, stream>>>(u, iidx, user_emb, z2, out);
}

// Round 4
// 603.727 us; speedup vs baseline: 2.1559x; 1.0180x over previous
//
#include <hip/hip_runtime.h>
#include <hip/hip_bf16.h>
#include <math.h>

// Problem constants (from reference)
constexpr int N_ENT = 100000;
constexpr int NEDGE = 1600000;
constexpr int BATCH = 8192;
constexpr int NBLK_SCAN = (N_ENT + 255) / 256;   // 391

// ---------------------------------------------------------------------------
// Workspace layout (4-byte units):
//  degi      : [0, 100000)            int   degree counts
//  dinv      : [100000, 200000)       float 1/sqrt(deg+1)
//  scale     : [200000, 300000)       float renorm scale per entity
//  fsc       : [300000, 400000)       float scale*dinv per entity
//  row_start : [400000, 500001)       int   CSR offsets (100001)
//  cursor    : [500004, 600004)       int   placement cursors
//  partials  : [600004, 600404)       int   per-block degree sums (391)
//  srcs      : [600404, 2200404)      int   CSR src ids
//  z / h2    : [2200408, 8600408)     float [N,64] (z, then reused as h2)
//  y1r / z2  : [8600408, 21400408)    float [N,128] y1r, then z2 in first half
// Total ~85.6 MB.

// K1: degree histogram
__global__ __launch_bounds__(256) void deg_count(const int* __restrict__ edges,
                                                 int* __restrict__ degi) {
    int e = blockIdx.x * 256 + threadIdx.x;
    if (e < NEDGE) atomicAdd(&degi[edges[NEDGE + e]], 1);
}

// K2: per-entity renorm scale + dinv + fused factor — one wave per row
__global__ __launch_bounds__(256) void scale_k(const float* __restrict__ emb,
                                               const int* __restrict__ degi,
                                               float* __restrict__ dinv,
                                               float* __restrict__ scale,
                                               float* __restrict__ fsc) {
    int gt   = blockIdx.x * 256 + threadIdx.x;
    int n    = gt >> 6;
    int lane = threadIdx.x & 63;
    float v = emb[(size_t)n * 64 + lane];
    float s = v * v;
#pragma unroll
    for (int o = 32; o > 0; o >>= 1) s += __shfl_xor(s, o, 64);
    if (lane == 0) {
        float nrm = sqrtf(s);
        float sc  = nrm > 1.0f ? 1.0f / nrm : 1.0f;
        float dv  = 1.0f / sqrtf((float)(degi[n] + 1));
        scale[n] = sc;
        dinv[n]  = dv;
        fsc[n]   = sc * dv;
    }
}

// K3a: per-block degree sums
__global__ __launch_bounds__(256) void scan_partials(const int* __restrict__ degi,
                                                     int* __restrict__ partials) {
    __shared__ int ws[4];
    int i = blockIdx.x * 256 + threadIdx.x;
    int v = (i < N_ENT) ? degi[i] : 0;
#pragma unroll
    for (int o = 32; o > 0; o >>= 1) v += __shfl_xor(v, o, 64);
    if ((threadIdx.x & 63) == 0) ws[threadIdx.x >> 6] = v;
    __syncthreads();
    if (threadIdx.x == 0) partials[blockIdx.x] = ws[0] + ws[1] + ws[2] + ws[3];
}

// K3b: single small block — exclusive scan of 391 partials (in place)
__global__ __launch_bounds__(512) void scan_offsets(int* __restrict__ partials,
                                                    int* __restrict__ row_start) {
    __shared__ int ts[512];
    int t = threadIdx.x;
    int v = (t < NBLK_SCAN) ? partials[t] : 0;
    ts[t] = v;
    __syncthreads();
    for (int off = 1; off < 512; off <<= 1) {
        int x = (t >= off) ? ts[t - off] : 0;
        __syncthreads();
        ts[t] += x;
        __syncthreads();
    }
    if (t < NBLK_SCAN) partials[t] = ts[t] - v;
    if (t == 0) row_start[N_ENT] = NEDGE;
}

// K3c: per-block exclusive scan + block offset -> row_start, cursor
__global__ __launch_bounds__(256) void scan_apply(const int* __restrict__ degi,
                                                  const int* __restrict__ partials,
                                                  int* __restrict__ row_start,
                                                  int* __restrict__ cursor) {
    __shared__ int ts[256];
    int t = threadIdx.x;
    int i = blockIdx.x * 256 + t;
    int v = (i < N_ENT) ? degi[i] : 0;
    ts[t] = v;
    __syncthreads();
    for (int off = 1; off < 256; off <<= 1) {
        int x = (t >= off) ? ts[t - off] : 0;
        __syncthreads();
        ts[t] += x;
        __syncthreads();
    }
    if (i < N_ENT) {
        int excl = ts[t] - v + partials[blockIdx.x];
        row_start[i] = excl;
        cursor[i]    = excl;
    }
}

// K4: CSR placement — ONE scattered 4B write per edge (src id only)
__global__ __launch_bounds__(256) void place_k(const int* __restrict__ edges,
                                               int* __restrict__ cursor,
                                               int* __restrict__ srcs) {
    int e = blockIdx.x * 256 + threadIdx.x;
    if (e >= NEDGE) return;
    int s = edges[e];
    int d = edges[NEDGE + e];
    int pos = atomicAdd(&cursor[d], 1);
    srcs[pos] = s;
}

// K5: layer-1 aggregate on RAW 64-dim input (scatter commuted before GEMM):
// z[d] = dinv[d] * sum_j fsc[s_j]*emb[s_j] + scale[d]*dinv[d]^2 * emb[d]
// Per 64 edges: coalesced load of ids + factors, then shuffle-broadcast.
__global__ __launch_bounds__(256) void reduce1_k(const int* __restrict__ row_start,
                                                 const int* __restrict__ srcs,
                                                 const float* __restrict__ fsc,
                                                 const float* __restrict__ emb,
                                                 const float* __restrict__ dinv,
                                                 const float* __restrict__ scale,
                                                 float* __restrict__ z) {
    int gt   = blockIdx.x * 256 + threadIdx.x;
    int dst  = gt >> 6;
    int lane = threadIdx.x & 63;
    int beg = row_start[dst];
    int end = row_start[dst + 1];
    float acc0 = 0.f, acc1 = 0.f;
    for (int base = beg; base < end; base += 64) {
        int cnt = end - base; if (cnt > 64) cnt = 64;
        int   s_v = 0;
        float f_v = 0.f;
        if (base + lane < end) {
            s_v = srcs[base + lane];
            f_v = fsc[s_v];
        }
        int jj = 0;
        for (; jj + 1 < cnt; jj += 2) {
            int   s0 = __shfl(s_v, jj, 64), s1 = __shfl(s_v, jj + 1, 64);
            float f0 = __shfl(f_v, jj, 64), f1 = __shfl(f_v, jj + 1, 64);
            acc0 += f0 * emb[(size_t)s0 * 64 + lane];
            acc1 += f1 * emb[(size_t)s1 * 64 + lane];
        }
        if (jj < cnt) {
            int   s0 = __shfl(s_v, jj, 64);
            float f0 = __shfl(f_v, jj, 64);
            acc0 += f0 * emb[(size_t)s0 * 64 + lane];
        }
    }
    float dv   = dinv[dst];
    float self = scale[dst] * dv * dv;
    z[(size_t)dst * 64 + lane] = dv * (acc0 + acc1) + self * emb[(size_t)dst * 64 + lane];
}

// K6: y1r = relu(z @ W1 + b1)   [N,64]@[64,128]
__global__ __launch_bounds__(256) void gemm1_relu(const float* __restrict__ z,
                                                  const float* __restrict__ W1g,
                                                  const float* __restrict__ b1,
                                                  float* __restrict__ y1r) {
    __shared__ float W[64 * 128];
    __shared__ float A[16 * 65];     // +1 pad
    int tid = threadIdx.x;
    for (int idx = tid; idx < 64 * 128; idx += 256) W[idx] = W1g[idx];
    int row0 = blockIdx.x * 16;
    for (int idx = tid; idx < 16 * 64; idx += 256) {
        int r = idx >> 6, c = idx & 63;
        A[r * 65 + c] = z[(size_t)(row0 + r) * 64 + c];
    }
    __syncthreads();
    int c    = tid & 127;
    int half = tid >> 7;
    float acc[8];
#pragma unroll
    for (int r = 0; r < 8; ++r) acc[r] = 0.f;
    for (int k = 0; k < 64; ++k) {
        float w = W[k * 128 + c];
#pragma unroll
        for (int r = 0; r < 8; ++r) acc[r] += A[(half * 8 + r) * 65 + k] * w;
    }
    float bb = b1[c];
#pragma unroll
    for (int r = 0; r < 8; ++r) {
        float v = acc[r] + bb;
        y1r[(size_t)(row0 + half * 8 + r) * 128 + c] = v > 0.f ? v : 0.f;
    }
}

// K7: h2 = y1r @ W2   [N,128]@[128,64]
__global__ __launch_bounds__(256) void gemm2_k(const float* __restrict__ y1r,
                                               const float* __restrict__ W2g,
                                               float* __restrict__ h2) {
    __shared__ float W[128 * 64];
    __shared__ float A[16 * 129];    // +1 pad
    int tid = threadIdx.x;
    for (int idx = tid; idx < 128 * 64; idx += 256) W[idx] = W2g[idx];
    int row0 = blockIdx.x * 16;
    for (int idx = tid; idx < 16 * 128; idx += 256) {
        int r = idx >> 7, c = idx & 127;
        A[r * 129 + c] = y1r[(size_t)(row0 + r) * 128 + c];
    }
    __syncthreads();
    int c   = tid & 63;
    int grp = tid >> 6;
    float acc[4];
#pragma unroll
    for (int r = 0; r < 4; ++r) acc[r] = 0.f;
    for (int k = 0; k < 128; ++k) {
        float w = W[k * 64 + c];
#pragma unroll
        for (int r = 0; r < 4; ++r) acc[r] += A[(grp * 4 + r) * 129 + k] * w;
    }
#pragma unroll
    for (int r = 0; r < 4; ++r)
        h2[(size_t)(row0 + grp * 4 + r) * 64 + c] = acc[r];
}

// K8: layer-2 aggregate:
// z2[d] = dinv[d]*sum_j dinv[s_j]*h2[s_j] + dinv[d]^2*h2[d] + b2
__global__ __launch_bounds__(256) void reduce2_k(const int* __restrict__ row_start,
                                                 const int* __restrict__ srcs,
                                                 const float* __restrict__ dinv,
                                                 const float* __restrict__ h2,
                                                 const float* __restrict__ b2,
                                                 float* __restrict__ z2) {
    int gt   = blockIdx.x * 256 + threadIdx.x;
    int dst  = gt >> 6;
    int lane = threadIdx.x & 63;
    int beg = row_start[dst];
    int end = row_start[dst + 1];
    float acc0 = 0.f, acc1 = 0.f;
    for (int base = beg; base < end; base += 64) {
        int cnt = end - base; if (cnt > 64) cnt = 64;
        int   s_v = 0;
        float f_v = 0.f;
        if (base + lane < end) {
            s_v = srcs[base + lane];
            f_v = dinv[s_v];
        }
        int jj = 0;
        for (; jj + 1 < cnt; jj += 2) {
            int   s0 = __shfl(s_v, jj, 64), s1 = __shfl(s_v, jj + 1, 64);
            float f0 = __shfl(f_v, jj, 64), f1 = __shfl(f_v, jj + 1, 64);
            acc0 += f0 * h2[(size_t)s0 * 64 + lane];
            acc1 += f1 * h2[(size_t)s1 * 64 + lane];
        }
        if (jj < cnt) {
            int   s0 = __shfl(s_v, jj, 64);
            float f0 = __shfl(f_v, jj, 64);
            acc0 += f0 * h2[(size_t)s0 * 64 + lane];
        }
    }
    float dv = dinv[dst];
    z2[(size_t)dst * 64 + lane] =
        dv * (acc0 + acc1) + dv * dv * h2[(size_t)dst * 64 + lane] + b2[lane];
}

// K9: final — renorm(user)·item, sigmoid; one wave per batch element
__global__ __launch_bounds__(256) void final_dot(const int* __restrict__ u,
                                                 const int* __restrict__ iidx,
                                                 const float* __restrict__ uemb,
                                                 const float* __restrict__ z2,
                                                 float* __restrict__ out) {
    int gt   = blockIdx.x * 256 + threadIdx.x;
    int b    = gt >> 6;
    int lane = threadIdx.x & 63;
    int ui = u[b];
    int it = iidx[b];
    float ue = uemb[(size_t)ui * 64 + lane];
    float iv = z2[(size_t)it * 64 + lane];
    float s1 = ue * ue;
    float s2 = ue * iv;
#pragma unroll
    for (int o = 32; o > 0; o >>= 1) {
        s1 += __shfl_xor(s1, o, 64);
        s2 += __shfl_xor(s2, o, 64);
    }
    if (lane == 0) {
        float nrm = sqrtf(s1);
        float sc  = nrm > 1.0f ? 1.0f / nrm : 1.0f;
        float uv  = s2 * sc;
        out[b] = 1.0f / (1.0f + expf(-uv));
    }
}

// ---------------------------------------------------------------------------
extern "C" void kernel_launch(void* const* d_in, const int* in_sizes, int n_in,
                              void* d_out, int out_size, void* d_ws, size_t ws_size,
                              hipStream_t stream) {
    const int*   u          = (const int*)d_in[0];
    const int*   iidx       = (const int*)d_in[1];
    const int*   edges      = (const int*)d_in[2];
    const float* user_emb   = (const float*)d_in[3];
    const float* entity_emb = (const float*)d_in[4];
    const float* W1         = (const float*)d_in[5];
    const float* b1         = (const float*)d_in[6];
    const float* W2         = (const float*)d_in[7];
    const float* b2         = (const float*)d_in[8];
    float*       out        = (float*)d_out;

    char* ws = (char*)d_ws;
    int*   degi      = (int*)  (ws);
    float* dinv      = (float*)(ws + 100000u * 4);
    float* scale     = (float*)(ws + 200000u * 4);
    float* fsc       = (float*)(ws + 300000u * 4);
    int*   row_start = (int*)  (ws + 400000u * 4);
    int*   cursor    = (int*)  (ws + 500004u * 4);
    int*   partials  = (int*)  (ws + 600004u * 4);
    int*   srcs      = (int*)  (ws + 600404u * 4);
    float* z         = (float*)(ws + 2200408u * 4);   // reused as h2
    float* y1r       = (float*)(ws + 8600408u * 4);   // reused as z2
    float* h2 = z;
    float* z2 = y1r;

    hipMemsetAsync(degi, 0, N_ENT * sizeof(int), stream);
    deg_count<<<NEDGE / 256, 256, 0, stream>>>(edges, degi);
    scale_k<<<N_ENT * 64 / 256, 256, 0, stream>>>(entity_emb, degi, dinv, scale, fsc);

    scan_partials<<<NBLK_SCAN, 256, 0, stream>>>(degi, partials);
    scan_offsets<<<1, 512, 0, stream>>>(partials, row_start);
    scan_apply<<<NBLK_SCAN, 256, 0, stream>>>(degi, partials, row_start, cursor);

    place_k<<<NEDGE / 256, 256, 0, stream>>>(edges, cursor, srcs);

    reduce1_k<<<N_ENT * 64 / 256, 256, 0, stream>>>(row_start, srcs, fsc, entity_emb,
                                                    dinv, scale, z);
    gemm1_relu<<<N_ENT / 16, 256, 0, stream>>>(z, W1, b1, y1r);
    gemm2_k<<<N_ENT / 16, 256, 0, stream>>>(y1r, W2, h2);
    reduce2_k<<<N_ENT * 64 / 256, 256, 0, stream>>>(row_start, srcs, dinv, h2, b2, z2);

    final_dot<<<BATCH * 64 / 256, 256, 0, stream>>>(u, iidx, user_emb, z2, out);
}